// Round 5
// baseline (437.203 us; speedup 1.0000x reference)
//
#include <hip/hip_runtime.h>
#include <math.h>

#define B_ 32
#define S_ 500
#define C_ 1024
#define H_ 16
#define D_ 64
#define M_ (B_ * S_)  // 16000
#define MP 16128      // M padded to 63*256 for 256-row tiles
#define SP 512        // padded S for transposed V (16B-aligned rows)

typedef _Float16 f16;
typedef f16 f16x8 __attribute__((ext_vector_type(8)));
typedef f16 f16x4 __attribute__((ext_vector_type(4)));
typedef float f32x4 __attribute__((ext_vector_type(4)));

#define GLOBAL_AS __attribute__((address_space(1)))
#define LDS_AS __attribute__((address_space(3)))

__device__ __forceinline__ void async_load16(const void* g, void* l) {
    __builtin_amdgcn_global_load_lds((const GLOBAL_AS void*)g, (LDS_AS void*)l, 16, 0, 0);
}
template <int N>
__device__ __forceinline__ void wait_vmcnt() {
    asm volatile("s_waitcnt vmcnt(%0)" ::"i"(N) : "memory");
}

// tag types for the masked/unmasked kt-iteration
struct MaskF { static constexpr bool value = false; };
struct MaskT { static constexpr bool value = true; };

// ---------------------------------------------------------------------------
// fp32 -> fp16 cast, 8 elems/thread; rows beyond n8_real zero-filled (M pad)
// ---------------------------------------------------------------------------
__global__ __launch_bounds__(256) void cast_rows(
    const float* __restrict__ in, f16* __restrict__ out, int n8_real, int n8_tot)
{
    int i = blockIdx.x * 256 + threadIdx.x;
    if (i >= n8_tot) return;
    f16x8 h;
    if (i < n8_real) {
        float4 a = ((const float4*)in)[2 * i];
        float4 b = ((const float4*)in)[2 * i + 1];
        h[0] = (f16)a.x; h[1] = (f16)a.y; h[2] = (f16)a.z; h[3] = (f16)a.w;
        h[4] = (f16)b.x; h[5] = (f16)b.y; h[6] = (f16)b.z; h[7] = (f16)b.w;
    } else {
        f16 z = (f16)0.f;
        h[0] = z; h[1] = z; h[2] = z; h[3] = z;
        h[4] = z; h[5] = z; h[6] = z; h[7] = z;
    }
    ((f16x8*)out)[i] = h;
}

// ---------------------------------------------------------------------------
// 4x W [k][n] fp32 -> transposed fp16 T [n][k]. block (32,8), tile 32x32,
// blockIdx.z selects the matrix.
// ---------------------------------------------------------------------------
__global__ __launch_bounds__(256) void castW_T4(
    const float* __restrict__ W0, const float* __restrict__ W1,
    const float* __restrict__ W2, const float* __restrict__ W3,
    f16* __restrict__ T0, f16* __restrict__ T1,
    f16* __restrict__ T2, f16* __restrict__ T3)
{
    __shared__ float t[32][33];
    const int z = blockIdx.z;
    const float* W = (z == 0) ? W0 : (z == 1) ? W1 : (z == 2) ? W2 : W3;
    f16* T = (z == 0) ? T0 : (z == 1) ? T1 : (z == 2) ? T2 : T3;
    const int n0 = blockIdx.x * 32, k0 = blockIdx.y * 32;
    const int tx = threadIdx.x, ty = threadIdx.y;
#pragma unroll
    for (int i = 0; i < 4; ++i)
        t[ty + 8 * i][tx] = W[(size_t)(k0 + ty + 8 * i) * C_ + n0 + tx];
    __syncthreads();
#pragma unroll
    for (int i = 0; i < 4; ++i) {
        int n = ty + 8 * i;
        T[(size_t)(n0 + n) * C_ + k0 + tx] = (f16)t[tx][n];
    }
}

// ---------------------------------------------------------------------------
// 256x256 fp16 MFMA GEMM, full-tile double-buffer with COUNTED vmcnt
// (unchanged from round 4 — verified correct; ~690 TF, 2-phase regime).
// MODE 0: fused QKV (N=3072, sec = n>>10 -> q*0.125 / k / v-transposed).
// MODE 1: final projection (N=1024), fp32 out.
// ---------------------------------------------------------------------------
#define BAR()                          \
    __builtin_amdgcn_s_barrier();      \
    __builtin_amdgcn_sched_barrier(0)

#define LD_A(MH)                                                              \
    _Pragma("unroll") for (int i = 0; i < 4; ++i)                             \
    _Pragma("unroll") for (int ks = 0; ks < 2; ++ks)                          \
        af[i][ks] = *(const f16x8*)(smem + c * 32768 + rowA +                 \
                                    ((MH) * 64 + i * 16) * 64 + sw[ks]);

#define LD_B(NH)                                                              \
    _Pragma("unroll") for (int j = 0; j < 2; ++j)                             \
    _Pragma("unroll") for (int ks = 0; ks < 2; ++ks)                          \
        bf[NH][j][ks] = *(const f16x8*)(smem + c * 32768 + rowB +             \
                                        ((NH) * 32 + j * 16) * 64 + sw[ks]);

#define MMA(MH, NH)                                                           \
    __builtin_amdgcn_s_setprio(1);                                            \
    _Pragma("unroll") for (int i = 0; i < 4; ++i)                             \
    _Pragma("unroll") for (int j = 0; j < 2; ++j)                             \
    _Pragma("unroll") for (int ks = 0; ks < 2; ++ks)                          \
        acc[(MH) * 4 + i][(NH) * 2 + j] =                                     \
            __builtin_amdgcn_mfma_f32_16x16x32_f16(                           \
                af[i][ks], bf[NH][j][ks], acc[(MH) * 4 + i][(NH) * 2 + j],    \
                0, 0, 0);                                                     \
    __builtin_amdgcn_s_setprio(0)

template <int MODE>
__global__ __launch_bounds__(512) void gemm256(
    const f16* __restrict__ A, const f16* __restrict__ W,
    const float* __restrict__ b0, const float* __restrict__ b1,
    const float* __restrict__ b2, void* __restrict__ o0,
    void* __restrict__ o1, void* __restrict__ o2)
{
    constexpr int K = C_;
    constexpr int NB = (MODE == 0) ? 12 : 4;   // 256-wide n-blocks
    constexpr int NWG = 63 * NB;
    constexpr int Q8 = NWG / 8, R8 = NWG % 8;
    extern __shared__ __align__(16) f16 smem[];  // [2][A 16384 | B 16384] f16

    const int tid = threadIdx.x;
    const int lane = tid & 63, w = tid >> 6;
    const int wm = w >> 2, wn = w & 3;  // 2 x 4 wave grid
    const int quad = lane >> 4, lr = lane & 15;

    // bijective XCD swizzle (m204)
    const int lin = blockIdx.x;
    const int xcd = lin & 7, pos = lin >> 3;
    const int wg = (xcd < R8 ? xcd * (Q8 + 1) : R8 * (Q8 + 1) + (xcd - R8) * Q8) + pos;
    const int m0 = (wg / NB) * 256;
    const int n0 = (wg % NB) * 256;

    // staging: thread covers (row = h*128 + it*64 + (tid>>3), slot j = tid&7),
    // global col-chunk = j ^ (row&7); LDS dest strictly linear in tid.
    const int srow = tid >> 3, sj = tid & 7;
    const int gc = sj ^ (srow & 7);
    const f16* pA = A + (size_t)(m0 + srow) * K + gc * 8;
    const f16* pB = W + (size_t)(n0 + srow) * K + gc * 8;
    f16* dA = smem + tid * 8;
    f16* dB = smem + 16384 + tid * 8;

    auto stageA = [&](int kt, int cb, int h) __attribute__((always_inline)) {
        const f16* s = pA + (size_t)(h * 128) * K + kt * 64;
        f16* d = dA + cb * 32768 + h * 8192;
        async_load16(s, d);
        async_load16(s + (size_t)64 * K, d + 4096);
    };
    auto stageB = [&](int kt, int cb, int h) __attribute__((always_inline)) {
        const f16* s = pB + (size_t)(h * 128) * K + kt * 64;
        f16* d = dB + cb * 32768 + h * 8192;
        async_load16(s, d);
        async_load16(s + (size_t)64 * K, d + 4096);
    };

    // ds_read swizzle: fragment row r has r&7 == lr&7, slot q read at q^(lr&7)
    int sw[2];
    sw[0] = ((0 + quad) ^ (lr & 7)) * 8;
    sw[1] = ((4 + quad) ^ (lr & 7)) * 8;
    const int rowA = (wm * 128 + lr) * 64;
    const int rowB = 16384 + (wn * 64 + lr) * 64;

    f32x4 acc[8][4];
#pragma unroll
    for (int i = 0; i < 8; ++i)
#pragma unroll
        for (int j = 0; j < 4; ++j) acc[i][j] = (f32x4)0.f;
    f16x8 af[4][2], bf[2][2][2];

    // prologue: stage tile 0 into buffer 0 (8 loads)
    stageA(0, 0, 0); stageA(0, 0, 1); stageB(0, 0, 0); stageB(0, 0, 1);

    constexpr int NT = K / 64;  // 16
    for (int kt = 0; kt < NT; ++kt) {
        const int c = kt & 1;
        BAR();  // all waves done reading buf c^1 -> safe to overwrite
        if (kt + 1 < NT) {
            stageA(kt + 1, c ^ 1, 0); stageA(kt + 1, c ^ 1, 1);
            stageB(kt + 1, c ^ 1, 0); stageB(kt + 1, c ^ 1, 1);
            wait_vmcnt<8>();  // drain tile kt; tile kt+1 stays in flight
        } else {
            wait_vmcnt<0>();  // last tile: full drain
        }
        BAR();  // tile kt in LDS, visible to all waves
        LD_A(0); LD_B(0);
        MMA(0, 0);
        LD_B(1);
        MMA(0, 1);
        LD_A(1);
        MMA(1, 1);
        MMA(1, 0);
    }

    // epilogue: C/D layout col=lane&15, row=quad*4+reg; rows >= M_ are pad
#pragma unroll
    for (int nf = 0; nf < 4; ++nf) {
        int gcn = n0 + wn * 64 + nf * 16 + lr;
        if (MODE == 1) {
            float bv = b0[gcn];
            float* of = (float*)o0;
#pragma unroll
            for (int mf = 0; mf < 8; ++mf) {
                int gr0 = m0 + wm * 128 + mf * 16 + quad * 4;
                if (gr0 >= M_) continue;
#pragma unroll
                for (int r = 0; r < 4; ++r)
                    of[(size_t)(gr0 + r) * C_ + gcn] = acc[mf][nf][r] + bv;
            }
        } else {
            int sec = gcn >> 10;  // uniform within a 16-col nf-tile
            int gcl = gcn & 1023;
            const float* bp = (sec == 0) ? b0 : (sec == 1) ? b1 : b2;
            float bv = bp[gcl];
            float osc = (sec == 0) ? 0.125f : 1.0f;
            int h = gcl >> 6, d = gcl & 63;
#pragma unroll
            for (int mf = 0; mf < 8; ++mf) {
                int gr0 = m0 + wm * 128 + mf * 16 + quad * 4;
                if (gr0 >= M_) continue;        // pad rows
                int b = gr0 / S_, s0 = gr0 - b * S_;  // never crosses batch
                if (sec < 2) {
                    f16* oq = (f16*)((sec == 0) ? o0 : o1);
#pragma unroll
                    for (int r = 0; r < 4; ++r) {
                        float v = (acc[mf][nf][r] + bv) * osc;
                        size_t idx = (((size_t)b * H_ + h) * S_ + (s0 + r)) * D_ + d;
                        oq[idx] = (f16)v;
                    }
                } else {
                    f16* ov = (f16*)o2;
                    f16x4 pk;
#pragma unroll
                    for (int r = 0; r < 4; ++r) pk[r] = (f16)(acc[mf][nf][r] + bv);
                    *(f16x4*)(ov + (((size_t)b * H_ + h) * D_ + d) * SP + s0) = pk;
                }
            }
        }
    }
}

// ---------------------------------------------------------------------------
// fp16 MFMA flash attention v3: NO K/V LDS staging, ZERO barriers.
// Per bh, K+V = 128 KB — L2-resident (XCD-grouped dispatch pins a bh's 4
// q-tile blocks to one XCD). K/V fragments are read directly from global
// (L2-hot, ~200cy, hidden by TLP); only P goes through LDS (wave-private,
// 16 KB). __launch_bounds__(256,4) caps VGPR at 128 -> 4 blocks/CU = 16
// fully independent waves/CU. s_setprio(1) wraps MFMA clusters (T5 regime:
// independent waves at different phases).
// ---------------------------------------------------------------------------
__global__ __launch_bounds__(256, 4) void attn_mfma(
    const f16* __restrict__ qg, const f16* __restrict__ kg,
    const f16* __restrict__ vt, f16* __restrict__ Y)
{
    __shared__ __align__(16) f16 sP[4 * 32 * 64];  // per-wave P[q=32][key=64]

    const int tid = threadIdx.x;
    const int lin = blockIdx.x;
    const int xcd = lin & 7;
    const int pos = lin >> 3;
    const int bh = xcd * 64 + (pos >> 2);
    const int qt = 3 - (pos & 3);   // interleave long/short blocks
    const int q0 = qt * 128;
    const int lane = tid & 63, w = tid >> 6;
    const int quad = lane >> 4, lr = lane & 15;
    const size_t gbase = (size_t)bh * S_ * D_;
    const size_t vbase = (size_t)bh * D_ * SP;
    const int psw = (lr & 7) << 1;

    // ---- Q fragments direct from global (once). q col = q0 + w*32 + t*16+lr.
    // Rows >= S_ read adjacent workspace (finite garbage); outputs discarded.
    f16x8 qf[2][2];  // [t][s2]
#pragma unroll
    for (int t = 0; t < 2; ++t) {
        int q = q0 + w * 32 + t * 16 + lr;
        const f16* pq = qg + gbase + (size_t)q * D_;
#pragma unroll
        for (int s2 = 0; s2 < 2; ++s2)
            qf[t][s2] = *(const f16x8*)(pq + quad * 8 + 32 * s2);
    }

    f32x4 accO[2][4];  // [t(q-16-block)][nt(d-16-block)]
#pragma unroll
    for (int t = 0; t < 2; ++t)
#pragma unroll
        for (int nt = 0; nt < 4; ++nt) accO[t][nt] = (f32x4)0.f;
    float l_run[2] = {0.f, 0.f};

    // one kt-iteration; MASKED=true only for the two diagonal tiles
    auto step = [&](int kt, auto masked_tag) __attribute__((always_inline)) {
        constexpr bool MASKED = decltype(masked_tag)::value;
        const int k0 = kt * 64;

        // S^T = K·Q^T : K fragments direct from global (L2-hot).
        // Row key = k0 + mt*16 + lr, cols quad*8 + 32*s2 (+8) — per row the
        // 4 quads cover 64B contiguous.
        f32x4 accS[4][2];
#pragma unroll
        for (int mt = 0; mt < 4; ++mt)
#pragma unroll
            for (int t = 0; t < 2; ++t) accS[mt][t] = (f32x4)0.f;
        __builtin_amdgcn_s_setprio(1);
#pragma unroll
        for (int mt = 0; mt < 4; ++mt) {
            const f16* pk_ = kg + gbase + (size_t)(k0 + mt * 16 + lr) * D_;
#pragma unroll
            for (int s2 = 0; s2 < 2; ++s2) {
                f16x8 ka = *(const f16x8*)(pk_ + quad * 8 + 32 * s2);
#pragma unroll
                for (int t = 0; t < 2; ++t)
                    accS[mt][t] = __builtin_amdgcn_mfma_f32_16x16x32_f16(
                        ka, qf[t][s2], accS[mt][t], 0, 0, 0);
            }
        }
        __builtin_amdgcn_s_setprio(0);

        // exp (no max subtraction), accumulate l, pack P to wave-private LDS
        float ls[2] = {0.f, 0.f};
#pragma unroll
        for (int mt = 0; mt < 4; ++mt)
#pragma unroll
            for (int t = 0; t < 2; ++t) {
                f16x4 pk;
#pragma unroll
                for (int r = 0; r < 4; ++r) {
                    float s = accS[mt][t][r];
                    if (MASKED) {
                        int key = k0 + mt * 16 + quad * 4 + r;
                        int qq = q0 + w * 32 + t * 16 + lr;
                        s = (key <= qq && key < S_) ? s : -1e30f;
                    }
                    float p = __expf(s);
                    ls[t] += p;
                    pk[r] = (f16)p;
                }
                int c8 = (mt * 4 + quad) ^ psw;
                *(f16x4*)&sP[w * 2048 + (t * 16 + lr) * 64 + c8 * 4] = pk;
            }
        ls[0] += __shfl_xor(ls[0], 16); ls[0] += __shfl_xor(ls[0], 32);
        ls[1] += __shfl_xor(ls[1], 16); ls[1] += __shfl_xor(ls[1], 32);
        l_run[0] += ls[0];
        l_run[1] += ls[1];

        // O += P·V (A=P wave-private LDS, B=Vt direct from global, L2-hot)
        __builtin_amdgcn_s_setprio(1);
#pragma unroll
        for (int t = 0; t < 2; ++t) {
            int pb = w * 2048 + (t * 16 + lr) * 64;
#pragma unroll
            for (int s2 = 0; s2 < 2; ++s2) {
                int c8 = (quad * 2 + 8 * s2) ^ psw;
                f16x8 pf = *(const f16x8*)&sP[pb + c8 * 4];
#pragma unroll
                for (int nt = 0; nt < 4; ++nt) {
                    f16x8 vf = *(const f16x8*)(vt + vbase +
                        (size_t)(nt * 16 + lr) * SP + k0 + quad * 8 + s2 * 32);
                    accO[t][nt] = __builtin_amdgcn_mfma_f32_16x16x32_f16(
                        pf, vf, accO[t][nt], 0, 0, 0);
                }
            }
        }
        __builtin_amdgcn_s_setprio(0);
    };

    for (int kt = 0; kt < 2 * qt; ++kt) step(kt, MaskF{});
    step(2 * qt, MaskT{});
    step(2 * qt + 1, MaskT{});

    // epilogue: O rows q = q0 + w*32 + t*16 + quad*4 + r, cols d = nt*16+lr
    const int b = bh >> 4, h = bh & 15;
#pragma unroll
    for (int t = 0; t < 2; ++t) {
#pragma unroll
        for (int r = 0; r < 4; ++r) {
            float lsum = __shfl(l_run[t], quad * 4 + r);
            float iv = 1.f / lsum;
            int s = q0 + w * 32 + t * 16 + quad * 4 + r;
            if (s >= S_) continue;
            size_t rowbase = (size_t)(b * S_ + s) * C_ + h * 64;
#pragma unroll
            for (int nt = 0; nt < 4; ++nt)
                Y[rowbase + nt * 16 + lr] = (f16)(accO[t][nt][r] * iv);
        }
    }
}

// ---------------------------------------------------------------------------
// Workspace (fp16): q,k (2xNEL) + vt (B*H*D*SP) + xf (MP*C, pad rows zeroed,
// reused as yf) + wpf (WEL) ~ 134 MB. Wq/Wk/Wv casts in d_out scratch
// (one contiguous [3072][1024] fp16 matrix, consumed before proj overwrites).
// ---------------------------------------------------------------------------
extern "C" void kernel_launch(void* const* d_in, const int* in_sizes, int n_in,
                              void* d_out, int out_size, void* d_ws, size_t ws_size,
                              hipStream_t stream)
{
    const float* x = (const float*)d_in[0];
    const float* Wq = (const float*)d_in[1];
    const float* bq = (const float*)d_in[2];
    const float* Wk = (const float*)d_in[3];
    const float* bk = (const float*)d_in[4];
    const float* Wv = (const float*)d_in[5];
    const float* bv = (const float*)d_in[6];
    const float* Wp = (const float*)d_in[7];
    const float* bp = (const float*)d_in[8];

    const size_t NEL = (size_t)M_ * C_;
    const size_t WEL = (size_t)C_ * C_;
    f16* qf = (f16*)d_ws;
    f16* kf = qf + NEL;
    f16* vtw = kf + NEL;
    f16* xf = vtw + (size_t)B_ * H_ * D_ * SP;
    f16* wpf = xf + (size_t)MP * C_;
    f16* yf = xf;  // alias: x cast dead after QKV GEMM

    f16* wq = (f16*)d_out;  // d_out as scratch until final GEMM
    f16* wk = wq + WEL;
    f16* wv = wk + WEL;

    hipFuncSetAttribute(reinterpret_cast<const void*>(&gemm256<0>),
                        hipFuncAttributeMaxDynamicSharedMemorySize, 131072);
    hipFuncSetAttribute(reinterpret_cast<const void*>(&gemm256<1>),
                        hipFuncAttributeMaxDynamicSharedMemorySize, 131072);

    castW_T4<<<dim3(32, 32, 4), dim3(32, 8), 0, stream>>>(
        Wq, Wk, Wv, Wp, wq, wk, wv, wpf);

    int n8r = (int)(NEL / 8);
    int n8t = (int)((size_t)MP * C_ / 8);
    cast_rows<<<(n8t + 255) / 256, 256, 0, stream>>>(x, xf, n8r, n8t);

    // fused QKV projection: N=3072, Q section carries the 0.125 softmax scale
    gemm256<0><<<756, 512, 131072, stream>>>(xf, wq, bq, bk, bv, qf, kf, vtw);

    attn_mfma<<<2048, 256, 0, stream>>>(qf, kf, vtw, yf);

    gemm256<1><<<252, 512, 131072, stream>>>(yf, wpf, bp, nullptr, nullptr,
                                             d_out, nullptr, nullptr);
}

// Round 6
// 368.647 us; speedup vs baseline: 1.1860x; 1.1860x over previous
//
#include <hip/hip_runtime.h>
#include <math.h>

#define B_ 32
#define S_ 500
#define C_ 1024
#define H_ 16
#define D_ 64
#define M_ (B_ * S_)  // 16000
#define MP 16128      // M padded to 63*256 for 256-row tiles
#define SP 512        // padded S for transposed V (16B-aligned rows)

typedef _Float16 f16;
typedef f16 f16x8 __attribute__((ext_vector_type(8)));
typedef f16 f16x4 __attribute__((ext_vector_type(4)));
typedef float f32x4 __attribute__((ext_vector_type(4)));

#define GLOBAL_AS __attribute__((address_space(1)))
#define LDS_AS __attribute__((address_space(3)))

__device__ __forceinline__ void async_load16(const void* g, void* l) {
    __builtin_amdgcn_global_load_lds((const GLOBAL_AS void*)g, (LDS_AS void*)l, 16, 0, 0);
}
template <int N>
__device__ __forceinline__ void wait_vmcnt() {
    asm volatile("s_waitcnt vmcnt(%0)" ::"i"(N) : "memory");
}

// tag types for the masked/unmasked kt-iteration
struct MaskF { static constexpr bool value = false; };
struct MaskT { static constexpr bool value = true; };

// ---------------------------------------------------------------------------
// Fused prep: blocks [0,4096) transpose+cast the 4 weight matrices
// (W [k][n] fp32 -> T [n][k] f16, 32x32 tiles); blocks [4096, ...) cast x
// rows fp32 -> f16 (8 elems/thread), zero-filling the M-pad rows.
// One launch instead of two (~10 us launch overhead each).
// ---------------------------------------------------------------------------
__global__ __launch_bounds__(256) void prep(
    const float* __restrict__ x, f16* __restrict__ xf, int n8_real, int n8_tot,
    const float* __restrict__ W0, const float* __restrict__ W1,
    const float* __restrict__ W2, const float* __restrict__ W3,
    f16* __restrict__ T0, f16* __restrict__ T1,
    f16* __restrict__ T2, f16* __restrict__ T3)
{
    __shared__ float t[32][33];
    const int bid = blockIdx.x;
    const int tid = threadIdx.x;
    if (bid < 4096) {
        const int z = bid >> 10, rem = bid & 1023;
        const float* W = (z == 0) ? W0 : (z == 1) ? W1 : (z == 2) ? W2 : W3;
        f16* T = (z == 0) ? T0 : (z == 1) ? T1 : (z == 2) ? T2 : T3;
        const int n0 = (rem & 31) * 32, k0 = (rem >> 5) * 32;
        const int tx = tid & 31, ty = tid >> 5;
#pragma unroll
        for (int i = 0; i < 4; ++i)
            t[ty + 8 * i][tx] = W[(size_t)(k0 + ty + 8 * i) * C_ + n0 + tx];
        __syncthreads();
#pragma unroll
        for (int i = 0; i < 4; ++i) {
            int n = ty + 8 * i;
            T[(size_t)(n0 + n) * C_ + k0 + tx] = (f16)t[tx][n];
        }
    } else {
        int i = (bid - 4096) * 256 + tid;
        if (i >= n8_tot) return;
        f16x8 h;
        if (i < n8_real) {
            float4 a = ((const float4*)x)[2 * i];
            float4 b = ((const float4*)x)[2 * i + 1];
            h[0] = (f16)a.x; h[1] = (f16)a.y; h[2] = (f16)a.z; h[3] = (f16)a.w;
            h[4] = (f16)b.x; h[5] = (f16)b.y; h[6] = (f16)b.z; h[7] = (f16)b.w;
        } else {
            f16 z8 = (f16)0.f;
            h[0] = z8; h[1] = z8; h[2] = z8; h[3] = z8;
            h[4] = z8; h[5] = z8; h[6] = z8; h[7] = z8;
        }
        ((f16x8*)xf)[i] = h;
    }
}

// ---------------------------------------------------------------------------
// 256x256 fp16 MFMA GEMM, full-tile double-buffer with COUNTED vmcnt
// (byte-identical to round 4 — verified correct; ~690 TF; serves as the
// machine-state canary this round).
// MODE 0: fused QKV (N=3072, sec = n>>10 -> q*0.125 / k / v-transposed).
// MODE 1: final projection (N=1024), fp32 out.
// ---------------------------------------------------------------------------
#define BAR()                          \
    __builtin_amdgcn_s_barrier();      \
    __builtin_amdgcn_sched_barrier(0)

#define LD_A(MH)                                                              \
    _Pragma("unroll") for (int i = 0; i < 4; ++i)                             \
    _Pragma("unroll") for (int ks = 0; ks < 2; ++ks)                          \
        af[i][ks] = *(const f16x8*)(smem + c * 32768 + rowA +                 \
                                    ((MH) * 64 + i * 16) * 64 + sw[ks]);

#define LD_B(NH)                                                              \
    _Pragma("unroll") for (int j = 0; j < 2; ++j)                             \
    _Pragma("unroll") for (int ks = 0; ks < 2; ++ks)                          \
        bf[NH][j][ks] = *(const f16x8*)(smem + c * 32768 + rowB +             \
                                        ((NH) * 32 + j * 16) * 64 + sw[ks]);

#define MMA(MH, NH)                                                           \
    __builtin_amdgcn_s_setprio(1);                                            \
    _Pragma("unroll") for (int i = 0; i < 4; ++i)                             \
    _Pragma("unroll") for (int j = 0; j < 2; ++j)                             \
    _Pragma("unroll") for (int ks = 0; ks < 2; ++ks)                          \
        acc[(MH) * 4 + i][(NH) * 2 + j] =                                     \
            __builtin_amdgcn_mfma_f32_16x16x32_f16(                           \
                af[i][ks], bf[NH][j][ks], acc[(MH) * 4 + i][(NH) * 2 + j],    \
                0, 0, 0);                                                     \
    __builtin_amdgcn_s_setprio(0)

template <int MODE>
__global__ __launch_bounds__(512) void gemm256(
    const f16* __restrict__ A, const f16* __restrict__ W,
    const float* __restrict__ b0, const float* __restrict__ b1,
    const float* __restrict__ b2, void* __restrict__ o0,
    void* __restrict__ o1, void* __restrict__ o2)
{
    constexpr int K = C_;
    constexpr int NB = (MODE == 0) ? 12 : 4;   // 256-wide n-blocks
    constexpr int NWG = 63 * NB;
    constexpr int Q8 = NWG / 8, R8 = NWG % 8;
    extern __shared__ __align__(16) f16 smem[];  // [2][A 16384 | B 16384] f16

    const int tid = threadIdx.x;
    const int lane = tid & 63, w = tid >> 6;
    const int wm = w >> 2, wn = w & 3;  // 2 x 4 wave grid
    const int quad = lane >> 4, lr = lane & 15;

    // bijective XCD swizzle (m204)
    const int lin = blockIdx.x;
    const int xcd = lin & 7, pos = lin >> 3;
    const int wg = (xcd < R8 ? xcd * (Q8 + 1) : R8 * (Q8 + 1) + (xcd - R8) * Q8) + pos;
    const int m0 = (wg / NB) * 256;
    const int n0 = (wg % NB) * 256;

    // staging: thread covers (row = h*128 + it*64 + (tid>>3), slot j = tid&7),
    // global col-chunk = j ^ (row&7); LDS dest strictly linear in tid.
    const int srow = tid >> 3, sj = tid & 7;
    const int gc = sj ^ (srow & 7);
    const f16* pA = A + (size_t)(m0 + srow) * K + gc * 8;
    const f16* pB = W + (size_t)(n0 + srow) * K + gc * 8;
    f16* dA = smem + tid * 8;
    f16* dB = smem + 16384 + tid * 8;

    auto stageA = [&](int kt, int cb, int h) __attribute__((always_inline)) {
        const f16* s = pA + (size_t)(h * 128) * K + kt * 64;
        f16* d = dA + cb * 32768 + h * 8192;
        async_load16(s, d);
        async_load16(s + (size_t)64 * K, d + 4096);
    };
    auto stageB = [&](int kt, int cb, int h) __attribute__((always_inline)) {
        const f16* s = pB + (size_t)(h * 128) * K + kt * 64;
        f16* d = dB + cb * 32768 + h * 8192;
        async_load16(s, d);
        async_load16(s + (size_t)64 * K, d + 4096);
    };

    // ds_read swizzle: fragment row r has r&7 == lr&7, slot q read at q^(lr&7)
    int sw[2];
    sw[0] = ((0 + quad) ^ (lr & 7)) * 8;
    sw[1] = ((4 + quad) ^ (lr & 7)) * 8;
    const int rowA = (wm * 128 + lr) * 64;
    const int rowB = 16384 + (wn * 64 + lr) * 64;

    f32x4 acc[8][4];
#pragma unroll
    for (int i = 0; i < 8; ++i)
#pragma unroll
        for (int j = 0; j < 4; ++j) acc[i][j] = (f32x4)0.f;
    f16x8 af[4][2], bf[2][2][2];

    // prologue: stage tile 0 into buffer 0 (8 loads)
    stageA(0, 0, 0); stageA(0, 0, 1); stageB(0, 0, 0); stageB(0, 0, 1);

    constexpr int NT = K / 64;  // 16
    for (int kt = 0; kt < NT; ++kt) {
        const int c = kt & 1;
        BAR();  // all waves done reading buf c^1 -> safe to overwrite
        if (kt + 1 < NT) {
            stageA(kt + 1, c ^ 1, 0); stageA(kt + 1, c ^ 1, 1);
            stageB(kt + 1, c ^ 1, 0); stageB(kt + 1, c ^ 1, 1);
            wait_vmcnt<8>();  // drain tile kt; tile kt+1 stays in flight
        } else {
            wait_vmcnt<0>();  // last tile: full drain
        }
        BAR();  // tile kt in LDS, visible to all waves
        LD_A(0); LD_B(0);
        MMA(0, 0);
        LD_B(1);
        MMA(0, 1);
        LD_A(1);
        MMA(1, 1);
        MMA(1, 0);
    }

    // epilogue: C/D layout col=lane&15, row=quad*4+reg; rows >= M_ are pad
#pragma unroll
    for (int nf = 0; nf < 4; ++nf) {
        int gcn = n0 + wn * 64 + nf * 16 + lr;
        if (MODE == 1) {
            float bv = b0[gcn];
            float* of = (float*)o0;
#pragma unroll
            for (int mf = 0; mf < 8; ++mf) {
                int gr0 = m0 + wm * 128 + mf * 16 + quad * 4;
                if (gr0 >= M_) continue;
#pragma unroll
                for (int r = 0; r < 4; ++r)
                    of[(size_t)(gr0 + r) * C_ + gcn] = acc[mf][nf][r] + bv;
            }
        } else {
            int sec = gcn >> 10;  // uniform within a 16-col nf-tile
            int gcl = gcn & 1023;
            const float* bp = (sec == 0) ? b0 : (sec == 1) ? b1 : b2;
            float bv = bp[gcl];
            float osc = (sec == 0) ? 0.125f : 1.0f;
            int h = gcl >> 6, d = gcl & 63;
#pragma unroll
            for (int mf = 0; mf < 8; ++mf) {
                int gr0 = m0 + wm * 128 + mf * 16 + quad * 4;
                if (gr0 >= M_) continue;        // pad rows
                int b = gr0 / S_, s0 = gr0 - b * S_;  // never crosses batch
                if (sec < 2) {
                    f16* oq = (f16*)((sec == 0) ? o0 : o1);
#pragma unroll
                    for (int r = 0; r < 4; ++r) {
                        float v = (acc[mf][nf][r] + bv) * osc;
                        size_t idx = (((size_t)b * H_ + h) * S_ + (s0 + r)) * D_ + d;
                        oq[idx] = (f16)v;
                    }
                } else {
                    f16* ov = (f16*)o2;
                    f16x4 pk;
#pragma unroll
                    for (int r = 0; r < 4; ++r) pk[r] = (f16)(acc[mf][nf][r] + bv);
                    *(f16x4*)(ov + (((size_t)b * H_ + h) * D_ + d) * SP + s0) = pk;
                }
            }
        }
    }
}

// ---------------------------------------------------------------------------
// fp16 MFMA flash attention — round-1 structure restored (measured 70.4 us):
// single-buffered K/V staging via global_load_lds, 32 KB LDS, 4 waves.
// Plus: XCD-grouped 1D dispatch (a bh's 4 q-tile blocks adjacent on one XCD
// -> K/V L2-hot; long/short blocks interleaved) and s_setprio(1) around the
// MFMA clusters (T5: independent blocks per CU arbitrate).
// ---------------------------------------------------------------------------
__global__ __launch_bounds__(256) void attn_mfma(
    const f16* __restrict__ qg, const f16* __restrict__ kg,
    const f16* __restrict__ vt, f16* __restrict__ Y)
{
    __shared__ __align__(16) f16 sK[64 * 64];
    __shared__ __align__(16) f16 sVt[64 * 64];
    __shared__ __align__(16) f16 sP[4 * 32 * 64];  // per-wave P[q=32][key=64]

    const int tid = threadIdx.x;
    const int lin = blockIdx.x;
    const int xcd = lin & 7;
    const int pos = lin >> 3;
    const int bh = xcd * 64 + (pos >> 2);
    const int qt = 3 - (pos & 3);   // interleave long/short blocks
    const int q0 = qt * 128;
    const int lane = tid & 63, w = tid >> 6;
    const int quad = lane >> 4, lr = lane & 15;
    const size_t gbase = (size_t)bh * S_ * D_;
    const size_t vbase = (size_t)bh * D_ * SP;
    const int psw = (lr & 7) << 1;

    // ---- Q fragments direct from global (once). q col = q0 + w*32 + t*16+lr.
    // Rows >= S_ read adjacent workspace (finite garbage); outputs discarded.
    f16x8 qf[2][2];  // [t][s2]
#pragma unroll
    for (int t = 0; t < 2; ++t) {
        int q = q0 + w * 32 + t * 16 + lr;
        const f16* pq = qg + gbase + (size_t)q * D_;
#pragma unroll
        for (int s2 = 0; s2 < 2; ++s2)
            qf[t][s2] = *(const f16x8*)(pq + quad * 8 + 32 * s2);
    }

    f32x4 accO[2][4];  // [t(q-16-block)][nt(d-16-block)]
#pragma unroll
    for (int t = 0; t < 2; ++t)
#pragma unroll
        for (int nt = 0; nt < 4; ++nt) accO[t][nt] = (f32x4)0.f;
    float l_run[2] = {0.f, 0.f};

    // one kt-iteration; MASKED=true only for the two diagonal tiles
    auto iter = [&](int kt, auto masked_tag) __attribute__((always_inline)) {
        constexpr bool MASKED = decltype(masked_tag)::value;
        const int k0 = kt * 64;
        // stage K + Vt via async DMA (swizzle on global side, LDS linear)
#pragma unroll
        for (int it = 0; it < 2; ++it) {
            int idx = it * 256 + tid;
            int row = idx >> 3, c = idx & 7;
            int csw = (c ^ (row & 7)) * 8;
            async_load16(kg + gbase + (size_t)(k0 + row) * D_ + csw, &sK[idx * 8]);
            async_load16(vt + vbase + (size_t)row * SP + k0 + csw, &sVt[idx * 8]);
        }
        __syncthreads();

        // S^T = K·Q^T : 4 key-tiles x 2 q-tiles x 2 K-steps
        f32x4 accS[4][2];
#pragma unroll
        for (int mt = 0; mt < 4; ++mt)
#pragma unroll
            for (int t = 0; t < 2; ++t) accS[mt][t] = (f32x4)0.f;
        __builtin_amdgcn_s_setprio(1);
#pragma unroll
        for (int mt = 0; mt < 4; ++mt) {
            int row = mt * 16 + lr;
#pragma unroll
            for (int s2 = 0; s2 < 2; ++s2) {
                int off = row * 64 + (((quad + 4 * s2) ^ (lr & 7)) << 3);
                f16x8 ka = *(const f16x8*)&sK[off];
#pragma unroll
                for (int t = 0; t < 2; ++t)
                    accS[mt][t] = __builtin_amdgcn_mfma_f32_16x16x32_f16(
                        ka, qf[t][s2], accS[mt][t], 0, 0, 0);
            }
        }
        __builtin_amdgcn_s_setprio(0);

        // exp (no max subtraction), accumulate l, pack P to wave-private LDS
        float ls[2] = {0.f, 0.f};
#pragma unroll
        for (int mt = 0; mt < 4; ++mt)
#pragma unroll
            for (int t = 0; t < 2; ++t) {
                f16x4 pk;
#pragma unroll
                for (int r = 0; r < 4; ++r) {
                    float s = accS[mt][t][r];
                    if (MASKED) {
                        int key = k0 + mt * 16 + quad * 4 + r;
                        int qq = q0 + w * 32 + t * 16 + lr;
                        s = (key <= qq && key < S_) ? s : -1e30f;
                    }
                    float p = __expf(s);
                    ls[t] += p;
                    pk[r] = (f16)p;
                }
                int c8 = (mt * 4 + quad) ^ psw;
                *(f16x4*)&sP[w * 2048 + (t * 16 + lr) * 64 + c8 * 4] = pk;
            }
        ls[0] += __shfl_xor(ls[0], 16); ls[0] += __shfl_xor(ls[0], 32);
        ls[1] += __shfl_xor(ls[1], 16); ls[1] += __shfl_xor(ls[1], 32);
        l_run[0] += ls[0];
        l_run[1] += ls[1];

        // O += P·V (A=P wave-private, B=Vt)
        __builtin_amdgcn_s_setprio(1);
#pragma unroll
        for (int t = 0; t < 2; ++t) {
            int pb = w * 2048 + (t * 16 + lr) * 64;
#pragma unroll
            for (int s2 = 0; s2 < 2; ++s2) {
                int c8 = (quad * 2 + 8 * s2) ^ psw;
                f16x8 pf = *(const f16x8*)&sP[pb + c8 * 4];
#pragma unroll
                for (int nt = 0; nt < 4; ++nt) {
                    f16x8 vf = *(const f16x8*)
                        &sVt[(nt * 16 + lr) * 64 + (((quad + 4 * s2) ^ (lr & 7)) << 3)];
                    accO[t][nt] = __builtin_amdgcn_mfma_f32_16x16x32_f16(
                        pf, vf, accO[t][nt], 0, 0, 0);
                }
            }
        }
        __builtin_amdgcn_s_setprio(0);
        __syncthreads();
    };

    for (int kt = 0; kt < 2 * qt; ++kt) iter(kt, MaskF{});
    iter(2 * qt, MaskT{});
    iter(2 * qt + 1, MaskT{});

    // epilogue: O rows q = q0 + w*32 + t*16 + quad*4 + r, cols d = nt*16+lr
    const int b = bh >> 4, h = bh & 15;
#pragma unroll
    for (int t = 0; t < 2; ++t) {
#pragma unroll
        for (int r = 0; r < 4; ++r) {
            float lsum = __shfl(l_run[t], quad * 4 + r);
            float iv = 1.f / lsum;
            int s = q0 + w * 32 + t * 16 + quad * 4 + r;
            if (s >= S_) continue;
            size_t rowbase = (size_t)(b * S_ + s) * C_ + h * 64;
#pragma unroll
            for (int nt = 0; nt < 4; ++nt)
                Y[rowbase + nt * 16 + lr] = (f16)(accO[t][nt][r] * iv);
        }
    }
}

// ---------------------------------------------------------------------------
// Workspace (fp16): q,k (2xNEL) + vt (B*H*D*SP) + xf (MP*C, pad rows zeroed,
// reused as yf) + wpf (WEL) ~ 134 MB. Wq/Wk/Wv casts in d_out scratch
// (one contiguous [3072][1024] fp16 matrix, consumed before proj overwrites).
// 4 launches total: prep, gemm<0>, attn, gemm<1>.
// ---------------------------------------------------------------------------
extern "C" void kernel_launch(void* const* d_in, const int* in_sizes, int n_in,
                              void* d_out, int out_size, void* d_ws, size_t ws_size,
                              hipStream_t stream)
{
    const float* x = (const float*)d_in[0];
    const float* Wq = (const float*)d_in[1];
    const float* bq = (const float*)d_in[2];
    const float* Wk = (const float*)d_in[3];
    const float* bk = (const float*)d_in[4];
    const float* Wv = (const float*)d_in[5];
    const float* bv = (const float*)d_in[6];
    const float* Wp = (const float*)d_in[7];
    const float* bp = (const float*)d_in[8];

    const size_t NEL = (size_t)M_ * C_;
    const size_t WEL = (size_t)C_ * C_;
    f16* qf = (f16*)d_ws;
    f16* kf = qf + NEL;
    f16* vtw = kf + NEL;
    f16* xf = vtw + (size_t)B_ * H_ * D_ * SP;
    f16* wpf = xf + (size_t)MP * C_;
    f16* yf = xf;  // alias: x cast dead after QKV GEMM

    f16* wq = (f16*)d_out;  // d_out as scratch until final GEMM
    f16* wk = wq + WEL;
    f16* wv = wk + WEL;

    hipFuncSetAttribute(reinterpret_cast<const void*>(&gemm256<0>),
                        hipFuncAttributeMaxDynamicSharedMemorySize, 131072);
    hipFuncSetAttribute(reinterpret_cast<const void*>(&gemm256<1>),
                        hipFuncAttributeMaxDynamicSharedMemorySize, 131072);

    int n8r = (int)(NEL / 8);
    int n8t = (int)((size_t)MP * C_ / 8);
    int nprep = 4096 + (n8t + 255) / 256;
    prep<<<nprep, 256, 0, stream>>>(x, xf, n8r, n8t,
                                    Wq, Wk, Wv, Wp, wq, wk, wv, wpf);

    // fused QKV projection: N=3072, Q section carries the 0.125 softmax scale
    gemm256<0><<<756, 512, 131072, stream>>>(xf, wq, bq, bk, bv, qf, kf, vtw);

    attn_mfma<<<2048, 256, 0, stream>>>(qf, kf, vtw, yf);

    gemm256<1><<<252, 512, 131072, stream>>>(yf, wpf, bp, nullptr, nullptr,
                                             d_out, nullptr, nullptr);
}

// Round 7
// 363.932 us; speedup vs baseline: 1.2013x; 1.0130x over previous
//
#include <hip/hip_runtime.h>
#include <math.h>

#define B_ 32
#define S_ 500
#define C_ 1024
#define H_ 16
#define D_ 64
#define M_ (B_ * S_)  // 16000
#define MP 16128      // M padded to 63*256 for 256-row tiles
#define SP 512        // padded S for transposed V (16B-aligned rows)

typedef _Float16 f16;
typedef f16 f16x8 __attribute__((ext_vector_type(8)));
typedef f16 f16x4 __attribute__((ext_vector_type(4)));
typedef float f32x4 __attribute__((ext_vector_type(4)));

#define GLOBAL_AS __attribute__((address_space(1)))
#define LDS_AS __attribute__((address_space(3)))

__device__ __forceinline__ void async_load16(const void* g, void* l) {
    __builtin_amdgcn_global_load_lds((const GLOBAL_AS void*)g, (LDS_AS void*)l, 16, 0, 0);
}
template <int N>
__device__ __forceinline__ void wait_vmcnt() {
    asm volatile("s_waitcnt vmcnt(%0)" ::"i"(N) : "memory");
}

// tag types for the masked/unmasked kt-iteration
struct MaskF { static constexpr bool value = false; };
struct MaskT { static constexpr bool value = true; };

// ---------------------------------------------------------------------------
// Fused prep: blocks [0,4096) transpose+cast the 4 weight matrices
// (W [k][n] fp32 -> T [n][k] f16, 32x32 tiles); blocks [4096, ...) cast x
// rows fp32 -> f16 (8 elems/thread), zero-filling the M-pad rows.
// ---------------------------------------------------------------------------
__global__ __launch_bounds__(256) void prep(
    const float* __restrict__ x, f16* __restrict__ xf, int n8_real, int n8_tot,
    const float* __restrict__ W0, const float* __restrict__ W1,
    const float* __restrict__ W2, const float* __restrict__ W3,
    f16* __restrict__ T0, f16* __restrict__ T1,
    f16* __restrict__ T2, f16* __restrict__ T3)
{
    __shared__ float t[32][33];
    const int bid = blockIdx.x;
    const int tid = threadIdx.x;
    if (bid < 4096) {
        const int z = bid >> 10, rem = bid & 1023;
        const float* W = (z == 0) ? W0 : (z == 1) ? W1 : (z == 2) ? W2 : W3;
        f16* T = (z == 0) ? T0 : (z == 1) ? T1 : (z == 2) ? T2 : T3;
        const int n0 = (rem & 31) * 32, k0 = (rem >> 5) * 32;
        const int tx = tid & 31, ty = tid >> 5;
#pragma unroll
        for (int i = 0; i < 4; ++i)
            t[ty + 8 * i][tx] = W[(size_t)(k0 + ty + 8 * i) * C_ + n0 + tx];
        __syncthreads();
#pragma unroll
        for (int i = 0; i < 4; ++i) {
            int n = ty + 8 * i;
            T[(size_t)(n0 + n) * C_ + k0 + tx] = (f16)t[tx][n];
        }
    } else {
        int i = (bid - 4096) * 256 + tid;
        if (i >= n8_tot) return;
        f16x8 h;
        if (i < n8_real) {
            float4 a = ((const float4*)x)[2 * i];
            float4 b = ((const float4*)x)[2 * i + 1];
            h[0] = (f16)a.x; h[1] = (f16)a.y; h[2] = (f16)a.z; h[3] = (f16)a.w;
            h[4] = (f16)b.x; h[5] = (f16)b.y; h[6] = (f16)b.z; h[7] = (f16)b.w;
        } else {
            f16 z8 = (f16)0.f;
            h[0] = z8; h[1] = z8; h[2] = z8; h[3] = z8;
            h[4] = z8; h[5] = z8; h[6] = z8; h[7] = z8;
        }
        ((f16x8*)xf)[i] = h;
    }
}

// ---------------------------------------------------------------------------
// 256x256 fp16 MFMA GEMM, 4-phase counted-vmcnt schedule (m201-style, with
// wave-coverage-correct chunking — the round-3 race fix).
//
// Staged CHUNKS (each 128 rows x 64 cols = 16 KB = 2 loads/thread), chosen so
// every chunk covers ALL 8 waves' corresponding phase reads:
//   A-chunk0 = rows {0-63, 128-191}   (= every wave's LD_A(0) rows wm*128+0..63)
//   A-chunk1 = rows {64-127, 192-255} (= LD_A(1))
//   B-chunk0 = rows {(r>>5)&1 == 0}   (= every wave's LD_B(0) rows wn*64+0..31)
//   B-chunk1 = rows {(r>>5)&1 == 1}   (= LD_B(1))
// Chunks are CONTIGUOUS in LDS (linear DMA dest); XOR col-swizzle key =
// within-chunk row & 7 == lr & 7 on the read side (pre-swizzled global src).
//
// Per K-tile t (buf c=t&1, staging t+1 into c^1), issue order Ac0,Bc0,Bc1,Ac1:
//   ph1: issue Ac0'; vmcnt(6); BAR; read Ac0,Bc0; MMA(0,0)
//   ph2: issue Bc0'; vmcnt(6); BAR; read Bc1;     MMA(0,1)
//   ph3: issue Bc1'; vmcnt(6); BAR; read Ac1;     MMA(1,1)
//   ph4: issue Ac1';                              MMA(1,0)   (regs only)
// vmcnt(6) always leaves exactly the 3 newest stage-calls in flight — by the
// issue stream, those are precisely the chunks no phase has consumed yet.
// Last tile peels with vmcnt 4 -> 2 -> 0. Accumulation order identical to the
// verified round-4 kernel.
// MODE 0: fused QKV (N=3072, sec = n>>10 -> q*0.125 / k / v-transposed).
// MODE 1: final projection (N=1024), fp32 out.
// ---------------------------------------------------------------------------
#define BAR()                          \
    __builtin_amdgcn_s_barrier();      \
    __builtin_amdgcn_sched_barrier(0)

#define LD_A(MH)                                                              \
    _Pragma("unroll") for (int i = 0; i < 4; ++i)                             \
    _Pragma("unroll") for (int ks = 0; ks < 2; ++ks)                          \
        af[i][ks] = *(const f16x8*)(smem + c * 32768 + (MH) * 8192 +          \
                                    rA_off + i * 1024 + sw[ks]);

#define LD_B(NH)                                                              \
    _Pragma("unroll") for (int j = 0; j < 2; ++j)                             \
    _Pragma("unroll") for (int ks = 0; ks < 2; ++ks)                          \
        bf[NH][j][ks] = *(const f16x8*)(smem + c * 32768 + 16384 +            \
                                        (NH) * 8192 + rB_off + j * 1024 +     \
                                        sw[ks]);

#define MMA(MH, NH)                                                           \
    __builtin_amdgcn_s_setprio(1);                                            \
    _Pragma("unroll") for (int i = 0; i < 4; ++i)                             \
    _Pragma("unroll") for (int j = 0; j < 2; ++j)                             \
    _Pragma("unroll") for (int ks = 0; ks < 2; ++ks)                          \
        acc[(MH) * 4 + i][(NH) * 2 + j] =                                     \
            __builtin_amdgcn_mfma_f32_16x16x32_f16(                           \
                af[i][ks], bf[NH][j][ks], acc[(MH) * 4 + i][(NH) * 2 + j],    \
                0, 0, 0);                                                     \
    __builtin_amdgcn_s_setprio(0)

template <int MODE>
__global__ __launch_bounds__(512) void gemm256(
    const f16* __restrict__ A, const f16* __restrict__ W,
    const float* __restrict__ b0, const float* __restrict__ b1,
    const float* __restrict__ b2, void* __restrict__ o0,
    void* __restrict__ o1, void* __restrict__ o2)
{
    constexpr int K = C_;
    constexpr int NB = (MODE == 0) ? 12 : 4;   // 256-wide n-blocks
    constexpr int NWG = 63 * NB;
    constexpr int Q8 = NWG / 8, R8 = NWG % 8;
    extern __shared__ __align__(16) f16 smem[];  // [2][A 16384 | B 16384] f16

    const int tid = threadIdx.x;
    const int lane = tid & 63, w = tid >> 6;
    const int wm = w >> 2, wn = w & 3;  // 2 x 4 wave grid
    const int quad = lane >> 4, lr = lane & 15;

    // bijective XCD swizzle (m204)
    const int lin = blockIdx.x;
    const int xcd = lin & 7, pos = lin >> 3;
    const int wg = (xcd < R8 ? xcd * (Q8 + 1) : R8 * (Q8 + 1) + (xcd - R8) * Q8) + pos;
    const int m0 = (wg / NB) * 256;
    const int n0 = (wg % NB) * 256;

    // staging: thread (srow = tid>>3, col8 = tid&7), pre-swizzled global col.
    // A chunk h, load l: global row = h*64 + srow + l*128; dest linear.
    // B chunk h, load l: global row = h*32 + (srow&31) + ((srow>>5)<<6) + l*128.
    const int srow = tid >> 3;
    const int gc8 = (tid & 7) ^ (srow & 7);
    const f16* pAt = A + (size_t)(m0 + srow) * K + gc8 * 8;
    const f16* pBt = W + (size_t)(n0 + (srow & 31) + ((srow >> 5) << 6)) * K + gc8 * 8;
    f16* dA = smem + tid * 8;
    f16* dB = smem + 16384 + tid * 8;

    auto stageA = [&](int kt, int cb, int h) __attribute__((always_inline)) {
        const f16* s = pAt + (size_t)(h * 64) * K + kt * 64;
        f16* d = dA + cb * 32768 + h * 8192;
        async_load16(s, d);
        async_load16(s + (size_t)128 * K, d + 4096);
    };
    auto stageB = [&](int kt, int cb, int h) __attribute__((always_inline)) {
        const f16* s = pBt + (size_t)(h * 32) * K + kt * 64;
        f16* d = dB + cb * 32768 + h * 8192;
        async_load16(s, d);
        async_load16(s + (size_t)128 * K, d + 4096);
    };

    // read-side: within-chunk row = wm*64 + i*16 + lr (A), wn*32 + j*16 + lr (B)
    int sw[2];
    sw[0] = ((0 + quad) ^ (lr & 7)) * 8;
    sw[1] = ((4 + quad) ^ (lr & 7)) * 8;
    const int rA_off = (wm * 64 + lr) * 64;
    const int rB_off = (wn * 32 + lr) * 64;

    f32x4 acc[8][4];
#pragma unroll
    for (int i = 0; i < 8; ++i)
#pragma unroll
        for (int j = 0; j < 4; ++j) acc[i][j] = (f32x4)0.f;
    f16x8 af[4][2], bf[2][2][2];

    // prologue: stage tile 0 into buf 0, issue order Ac0,Bc0,Bc1,Ac1
    stageA(0, 0, 0); stageB(0, 0, 0); stageB(0, 0, 1); stageA(0, 0, 1);

    constexpr int NT = K / 64;  // 16
    for (int kt = 0; kt < NT - 1; ++kt) {
        const int c = kt & 1, nb = c ^ 1;
        // ph1
        stageA(kt + 1, nb, 0);
        wait_vmcnt<6>(); BAR();
        LD_A(0); LD_B(0);
        MMA(0, 0);
        // ph2
        stageB(kt + 1, nb, 0);
        wait_vmcnt<6>(); BAR();
        LD_B(1);
        MMA(0, 1);
        // ph3
        stageB(kt + 1, nb, 1);
        wait_vmcnt<6>(); BAR();
        LD_A(1);
        MMA(1, 1);
        // ph4 (register-only MFMA; stage issue overlaps)
        stageA(kt + 1, nb, 1);
        MMA(1, 0);
    }
    {   // peeled last tile: drain 4 -> 2 -> 0
        const int c = (NT - 1) & 1;
        wait_vmcnt<4>(); BAR();
        LD_A(0); LD_B(0);
        MMA(0, 0);
        wait_vmcnt<2>(); BAR();
        LD_B(1);
        MMA(0, 1);
        wait_vmcnt<0>(); BAR();
        LD_A(1);
        MMA(1, 1);
        MMA(1, 0);
    }

    // epilogue: C/D layout col=lane&15, row=quad*4+reg; rows >= M_ are pad
#pragma unroll
    for (int nf = 0; nf < 4; ++nf) {
        int gcn = n0 + wn * 64 + nf * 16 + lr;
        if (MODE == 1) {
            float bv = b0[gcn];
            float* of = (float*)o0;
#pragma unroll
            for (int mf = 0; mf < 8; ++mf) {
                int gr0 = m0 + wm * 128 + mf * 16 + quad * 4;
                if (gr0 >= M_) continue;
#pragma unroll
                for (int r = 0; r < 4; ++r)
                    of[(size_t)(gr0 + r) * C_ + gcn] = acc[mf][nf][r] + bv;
            }
        } else {
            int sec = gcn >> 10;  // uniform within a 16-col nf-tile
            int gcl = gcn & 1023;
            const float* bp = (sec == 0) ? b0 : (sec == 1) ? b1 : b2;
            float bv = bp[gcl];
            float osc = (sec == 0) ? 0.125f : 1.0f;
            int h = gcl >> 6, d = gcl & 63;
#pragma unroll
            for (int mf = 0; mf < 8; ++mf) {
                int gr0 = m0 + wm * 128 + mf * 16 + quad * 4;
                if (gr0 >= M_) continue;        // pad rows
                int b = gr0 / S_, s0 = gr0 - b * S_;  // never crosses batch
                if (sec < 2) {
                    f16* oq = (f16*)((sec == 0) ? o0 : o1);
#pragma unroll
                    for (int r = 0; r < 4; ++r) {
                        float v = (acc[mf][nf][r] + bv) * osc;
                        size_t idx = (((size_t)b * H_ + h) * S_ + (s0 + r)) * D_ + d;
                        oq[idx] = (f16)v;
                    }
                } else {
                    f16* ov = (f16*)o2;
                    f16x4 pk;
#pragma unroll
                    for (int r = 0; r < 4; ++r) pk[r] = (f16)(acc[mf][nf][r] + bv);
                    *(f16x4*)(ov + (((size_t)b * H_ + h) * D_ + d) * SP + s0) = pk;
                }
            }
        }
    }
}

// ---------------------------------------------------------------------------
// fp16 MFMA flash attention — unchanged from round 6 (in current best config).
// ---------------------------------------------------------------------------
__global__ __launch_bounds__(256) void attn_mfma(
    const f16* __restrict__ qg, const f16* __restrict__ kg,
    const f16* __restrict__ vt, f16* __restrict__ Y)
{
    __shared__ __align__(16) f16 sK[64 * 64];
    __shared__ __align__(16) f16 sVt[64 * 64];
    __shared__ __align__(16) f16 sP[4 * 32 * 64];  // per-wave P[q=32][key=64]

    const int tid = threadIdx.x;
    const int lin = blockIdx.x;
    const int xcd = lin & 7;
    const int pos = lin >> 3;
    const int bh = xcd * 64 + (pos >> 2);
    const int qt = 3 - (pos & 3);   // interleave long/short blocks
    const int q0 = qt * 128;
    const int lane = tid & 63, w = tid >> 6;
    const int quad = lane >> 4, lr = lane & 15;
    const size_t gbase = (size_t)bh * S_ * D_;
    const size_t vbase = (size_t)bh * D_ * SP;
    const int psw = (lr & 7) << 1;

    f16x8 qf[2][2];  // [t][s2]
#pragma unroll
    for (int t = 0; t < 2; ++t) {
        int q = q0 + w * 32 + t * 16 + lr;
        const f16* pq = qg + gbase + (size_t)q * D_;
#pragma unroll
        for (int s2 = 0; s2 < 2; ++s2)
            qf[t][s2] = *(const f16x8*)(pq + quad * 8 + 32 * s2);
    }

    f32x4 accO[2][4];
#pragma unroll
    for (int t = 0; t < 2; ++t)
#pragma unroll
        for (int nt = 0; nt < 4; ++nt) accO[t][nt] = (f32x4)0.f;
    float l_run[2] = {0.f, 0.f};

    auto iter = [&](int kt, auto masked_tag) __attribute__((always_inline)) {
        constexpr bool MASKED = decltype(masked_tag)::value;
        const int k0 = kt * 64;
#pragma unroll
        for (int it = 0; it < 2; ++it) {
            int idx = it * 256 + tid;
            int row = idx >> 3, c = idx & 7;
            int csw = (c ^ (row & 7)) * 8;
            async_load16(kg + gbase + (size_t)(k0 + row) * D_ + csw, &sK[idx * 8]);
            async_load16(vt + vbase + (size_t)row * SP + k0 + csw, &sVt[idx * 8]);
        }
        __syncthreads();

        f32x4 accS[4][2];
#pragma unroll
        for (int mt = 0; mt < 4; ++mt)
#pragma unroll
            for (int t = 0; t < 2; ++t) accS[mt][t] = (f32x4)0.f;
        __builtin_amdgcn_s_setprio(1);
#pragma unroll
        for (int mt = 0; mt < 4; ++mt) {
            int row = mt * 16 + lr;
#pragma unroll
            for (int s2 = 0; s2 < 2; ++s2) {
                int off = row * 64 + (((quad + 4 * s2) ^ (lr & 7)) << 3);
                f16x8 ka = *(const f16x8*)&sK[off];
#pragma unroll
                for (int t = 0; t < 2; ++t)
                    accS[mt][t] = __builtin_amdgcn_mfma_f32_16x16x32_f16(
                        ka, qf[t][s2], accS[mt][t], 0, 0, 0);
            }
        }
        __builtin_amdgcn_s_setprio(0);

        float ls[2] = {0.f, 0.f};
#pragma unroll
        for (int mt = 0; mt < 4; ++mt)
#pragma unroll
            for (int t = 0; t < 2; ++t) {
                f16x4 pk;
#pragma unroll
                for (int r = 0; r < 4; ++r) {
                    float s = accS[mt][t][r];
                    if (MASKED) {
                        int key = k0 + mt * 16 + quad * 4 + r;
                        int qq = q0 + w * 32 + t * 16 + lr;
                        s = (key <= qq && key < S_) ? s : -1e30f;
                    }
                    float p = __expf(s);
                    ls[t] += p;
                    pk[r] = (f16)p;
                }
                int c8 = (mt * 4 + quad) ^ psw;
                *(f16x4*)&sP[w * 2048 + (t * 16 + lr) * 64 + c8 * 4] = pk;
            }
        ls[0] += __shfl_xor(ls[0], 16); ls[0] += __shfl_xor(ls[0], 32);
        ls[1] += __shfl_xor(ls[1], 16); ls[1] += __shfl_xor(ls[1], 32);
        l_run[0] += ls[0];
        l_run[1] += ls[1];

        __builtin_amdgcn_s_setprio(1);
#pragma unroll
        for (int t = 0; t < 2; ++t) {
            int pb = w * 2048 + (t * 16 + lr) * 64;
#pragma unroll
            for (int s2 = 0; s2 < 2; ++s2) {
                int c8 = (quad * 2 + 8 * s2) ^ psw;
                f16x8 pf = *(const f16x8*)&sP[pb + c8 * 4];
#pragma unroll
                for (int nt = 0; nt < 4; ++nt) {
                    f16x8 vf = *(const f16x8*)
                        &sVt[(nt * 16 + lr) * 64 + (((quad + 4 * s2) ^ (lr & 7)) << 3)];
                    accO[t][nt] = __builtin_amdgcn_mfma_f32_16x16x32_f16(
                        pf, vf, accO[t][nt], 0, 0, 0);
                }
            }
        }
        __builtin_amdgcn_s_setprio(0);
        __syncthreads();
    };

    for (int kt = 0; kt < 2 * qt; ++kt) iter(kt, MaskF{});
    iter(2 * qt, MaskT{});
    iter(2 * qt + 1, MaskT{});

    const int b = bh >> 4, h = bh & 15;
#pragma unroll
    for (int t = 0; t < 2; ++t) {
#pragma unroll
        for (int r = 0; r < 4; ++r) {
            float lsum = __shfl(l_run[t], quad * 4 + r);
            float iv = 1.f / lsum;
            int s = q0 + w * 32 + t * 16 + quad * 4 + r;
            if (s >= S_) continue;
            size_t rowbase = (size_t)(b * S_ + s) * C_ + h * 64;
#pragma unroll
            for (int nt = 0; nt < 4; ++nt)
                Y[rowbase + nt * 16 + lr] = (f16)(accO[t][nt][r] * iv);
        }
    }
}

// ---------------------------------------------------------------------------
// Workspace (fp16): q,k (2xNEL) + vt (B*H*D*SP) + xf (MP*C, pad rows zeroed,
// reused as yf) + wpf (WEL) ~ 134 MB. Wq/Wk/Wv casts in d_out scratch.
// 4 launches total: prep, gemm<0>, attn, gemm<1>.
// ---------------------------------------------------------------------------
extern "C" void kernel_launch(void* const* d_in, const int* in_sizes, int n_in,
                              void* d_out, int out_size, void* d_ws, size_t ws_size,
                              hipStream_t stream)
{
    const float* x = (const float*)d_in[0];
    const float* Wq = (const float*)d_in[1];
    const float* bq = (const float*)d_in[2];
    const float* Wk = (const float*)d_in[3];
    const float* bk = (const float*)d_in[4];
    const float* Wv = (const float*)d_in[5];
    const float* bv = (const float*)d_in[6];
    const float* Wp = (const float*)d_in[7];
    const float* bp = (const float*)d_in[8];

    const size_t NEL = (size_t)M_ * C_;
    const size_t WEL = (size_t)C_ * C_;
    f16* qf = (f16*)d_ws;
    f16* kf = qf + NEL;
    f16* vtw = kf + NEL;
    f16* xf = vtw + (size_t)B_ * H_ * D_ * SP;
    f16* wpf = xf + (size_t)MP * C_;
    f16* yf = xf;  // alias: x cast dead after QKV GEMM

    f16* wq = (f16*)d_out;  // d_out as scratch until final GEMM
    f16* wk = wq + WEL;
    f16* wv = wk + WEL;

    hipFuncSetAttribute(reinterpret_cast<const void*>(&gemm256<0>),
                        hipFuncAttributeMaxDynamicSharedMemorySize, 131072);
    hipFuncSetAttribute(reinterpret_cast<const void*>(&gemm256<1>),
                        hipFuncAttributeMaxDynamicSharedMemorySize, 131072);

    int n8r = (int)(NEL / 8);
    int n8t = (int)((size_t)MP * C_ / 8);
    int nprep = 4096 + (n8t + 255) / 256;
    prep<<<nprep, 256, 0, stream>>>(x, xf, n8r, n8t,
                                    Wq, Wk, Wv, Wp, wq, wk, wv, wpf);

    // fused QKV projection: N=3072, Q section carries the 0.125 softmax scale
    gemm256<0><<<756, 512, 131072, stream>>>(xf, wq, bq, bk, bv, qf, kf, vtw);

    attn_mfma<<<2048, 256, 0, stream>>>(qf, kf, vtw, yf);

    gemm256<1><<<252, 512, 131072, stream>>>(yf, wpf, bp, nullptr, nullptr,
                                             d_out, nullptr, nullptr);
}

// Round 8
// 358.240 us; speedup vs baseline: 1.2204x; 1.0159x over previous
//
#include <hip/hip_runtime.h>
#include <math.h>

#define B_ 32
#define S_ 500
#define C_ 1024
#define H_ 16
#define D_ 64
#define M_ (B_ * S_)  // 16000
#define MP 16128      // M padded to 63*256 for 256-row tiles
#define SP 512        // padded S for transposed V (16B-aligned rows)

typedef _Float16 f16;
typedef f16 f16x8 __attribute__((ext_vector_type(8)));
typedef f16 f16x4 __attribute__((ext_vector_type(4)));
typedef float f32x4 __attribute__((ext_vector_type(4)));

#define GLOBAL_AS __attribute__((address_space(1)))
#define LDS_AS __attribute__((address_space(3)))

__device__ __forceinline__ void async_load16(const void* g, void* l) {
    __builtin_amdgcn_global_load_lds((const GLOBAL_AS void*)g, (LDS_AS void*)l, 16, 0, 0);
}
template <int N>
__device__ __forceinline__ void wait_vmcnt() {
    asm volatile("s_waitcnt vmcnt(%0)" ::"i"(N) : "memory");
}

// tag types for the masked/unmasked kt-iteration
struct MaskF { static constexpr bool value = false; };
struct MaskT { static constexpr bool value = true; };

// ---------------------------------------------------------------------------
// Fused prep: blocks [0,4096) transpose+cast the 4 weight matrices
// (W [k][n] fp32 -> T [n][k] f16, 32x32 tiles); blocks [4096, ...) cast x
// rows fp32 -> f16 (8 elems/thread), zero-filling the M-pad rows.
// ---------------------------------------------------------------------------
__global__ __launch_bounds__(256) void prep(
    const float* __restrict__ x, f16* __restrict__ xf, int n8_real, int n8_tot,
    const float* __restrict__ W0, const float* __restrict__ W1,
    const float* __restrict__ W2, const float* __restrict__ W3,
    f16* __restrict__ T0, f16* __restrict__ T1,
    f16* __restrict__ T2, f16* __restrict__ T3)
{
    __shared__ float t[32][33];
    const int bid = blockIdx.x;
    const int tid = threadIdx.x;
    if (bid < 4096) {
        const int z = bid >> 10, rem = bid & 1023;
        const float* W = (z == 0) ? W0 : (z == 1) ? W1 : (z == 2) ? W2 : W3;
        f16* T = (z == 0) ? T0 : (z == 1) ? T1 : (z == 2) ? T2 : T3;
        const int n0 = (rem & 31) * 32, k0 = (rem >> 5) * 32;
        const int tx = tid & 31, ty = tid >> 5;
#pragma unroll
        for (int i = 0; i < 4; ++i)
            t[ty + 8 * i][tx] = W[(size_t)(k0 + ty + 8 * i) * C_ + n0 + tx];
        __syncthreads();
#pragma unroll
        for (int i = 0; i < 4; ++i) {
            int n = ty + 8 * i;
            T[(size_t)(n0 + n) * C_ + k0 + tx] = (f16)t[tx][n];
        }
    } else {
        int i = (bid - 4096) * 256 + tid;
        if (i >= n8_tot) return;
        f16x8 h;
        if (i < n8_real) {
            float4 a = ((const float4*)x)[2 * i];
            float4 b = ((const float4*)x)[2 * i + 1];
            h[0] = (f16)a.x; h[1] = (f16)a.y; h[2] = (f16)a.z; h[3] = (f16)a.w;
            h[4] = (f16)b.x; h[5] = (f16)b.y; h[6] = (f16)b.z; h[7] = (f16)b.w;
        } else {
            f16 z8 = (f16)0.f;
            h[0] = z8; h[1] = z8; h[2] = z8; h[3] = z8;
            h[4] = z8; h[5] = z8; h[6] = z8; h[7] = z8;
        }
        ((f16x8*)xf)[i] = h;
    }
}

// ---------------------------------------------------------------------------
// 256x256 fp16 MFMA GEMM, 4-phase counted-vmcnt schedule — byte-identical to
// round 7 (verified; ~760 TF; canary this round).
// MODE 0: fused QKV (N=3072, sec = n>>10 -> q*0.125 / k / v-transposed).
// MODE 1: final projection (N=1024), fp32 out.
// ---------------------------------------------------------------------------
#define BAR()                          \
    __builtin_amdgcn_s_barrier();      \
    __builtin_amdgcn_sched_barrier(0)

#define LD_A(MH)                                                              \
    _Pragma("unroll") for (int i = 0; i < 4; ++i)                             \
    _Pragma("unroll") for (int ks = 0; ks < 2; ++ks)                          \
        af[i][ks] = *(const f16x8*)(smem + c * 32768 + (MH) * 8192 +          \
                                    rA_off + i * 1024 + sw[ks]);

#define LD_B(NH)                                                              \
    _Pragma("unroll") for (int j = 0; j < 2; ++j)                             \
    _Pragma("unroll") for (int ks = 0; ks < 2; ++ks)                          \
        bf[NH][j][ks] = *(const f16x8*)(smem + c * 32768 + 16384 +            \
                                        (NH) * 8192 + rB_off + j * 1024 +     \
                                        sw[ks]);

#define MMA(MH, NH)                                                           \
    __builtin_amdgcn_s_setprio(1);                                            \
    _Pragma("unroll") for (int i = 0; i < 4; ++i)                             \
    _Pragma("unroll") for (int j = 0; j < 2; ++j)                             \
    _Pragma("unroll") for (int ks = 0; ks < 2; ++ks)                          \
        acc[(MH) * 4 + i][(NH) * 2 + j] =                                     \
            __builtin_amdgcn_mfma_f32_16x16x32_f16(                           \
                af[i][ks], bf[NH][j][ks], acc[(MH) * 4 + i][(NH) * 2 + j],    \
                0, 0, 0);                                                     \
    __builtin_amdgcn_s_setprio(0)

template <int MODE>
__global__ __launch_bounds__(512) void gemm256(
    const f16* __restrict__ A, const f16* __restrict__ W,
    const float* __restrict__ b0, const float* __restrict__ b1,
    const float* __restrict__ b2, void* __restrict__ o0,
    void* __restrict__ o1, void* __restrict__ o2)
{
    constexpr int K = C_;
    constexpr int NB = (MODE == 0) ? 12 : 4;   // 256-wide n-blocks
    constexpr int NWG = 63 * NB;
    constexpr int Q8 = NWG / 8, R8 = NWG % 8;
    extern __shared__ __align__(16) f16 smem[];  // [2][A 16384 | B 16384] f16

    const int tid = threadIdx.x;
    const int lane = tid & 63, w = tid >> 6;
    const int wm = w >> 2, wn = w & 3;  // 2 x 4 wave grid
    const int quad = lane >> 4, lr = lane & 15;

    // bijective XCD swizzle (m204)
    const int lin = blockIdx.x;
    const int xcd = lin & 7, pos = lin >> 3;
    const int wg = (xcd < R8 ? xcd * (Q8 + 1) : R8 * (Q8 + 1) + (xcd - R8) * Q8) + pos;
    const int m0 = (wg / NB) * 256;
    const int n0 = (wg % NB) * 256;

    // staging: thread (srow = tid>>3, col8 = tid&7), pre-swizzled global col.
    const int srow = tid >> 3;
    const int gc8 = (tid & 7) ^ (srow & 7);
    const f16* pAt = A + (size_t)(m0 + srow) * K + gc8 * 8;
    const f16* pBt = W + (size_t)(n0 + (srow & 31) + ((srow >> 5) << 6)) * K + gc8 * 8;
    f16* dA = smem + tid * 8;
    f16* dB = smem + 16384 + tid * 8;

    auto stageA = [&](int kt, int cb, int h) __attribute__((always_inline)) {
        const f16* s = pAt + (size_t)(h * 64) * K + kt * 64;
        f16* d = dA + cb * 32768 + h * 8192;
        async_load16(s, d);
        async_load16(s + (size_t)128 * K, d + 4096);
    };
    auto stageB = [&](int kt, int cb, int h) __attribute__((always_inline)) {
        const f16* s = pBt + (size_t)(h * 32) * K + kt * 64;
        f16* d = dB + cb * 32768 + h * 8192;
        async_load16(s, d);
        async_load16(s + (size_t)128 * K, d + 4096);
    };

    int sw[2];
    sw[0] = ((0 + quad) ^ (lr & 7)) * 8;
    sw[1] = ((4 + quad) ^ (lr & 7)) * 8;
    const int rA_off = (wm * 64 + lr) * 64;
    const int rB_off = (wn * 32 + lr) * 64;

    f32x4 acc[8][4];
#pragma unroll
    for (int i = 0; i < 8; ++i)
#pragma unroll
        for (int j = 0; j < 4; ++j) acc[i][j] = (f32x4)0.f;
    f16x8 af[4][2], bf[2][2][2];

    // prologue: stage tile 0 into buf 0, issue order Ac0,Bc0,Bc1,Ac1
    stageA(0, 0, 0); stageB(0, 0, 0); stageB(0, 0, 1); stageA(0, 0, 1);

    constexpr int NT = K / 64;  // 16
    for (int kt = 0; kt < NT - 1; ++kt) {
        const int c = kt & 1, nb = c ^ 1;
        // ph1
        stageA(kt + 1, nb, 0);
        wait_vmcnt<6>(); BAR();
        LD_A(0); LD_B(0);
        MMA(0, 0);
        // ph2
        stageB(kt + 1, nb, 0);
        wait_vmcnt<6>(); BAR();
        LD_B(1);
        MMA(0, 1);
        // ph3
        stageB(kt + 1, nb, 1);
        wait_vmcnt<6>(); BAR();
        LD_A(1);
        MMA(1, 1);
        // ph4 (register-only MFMA; stage issue overlaps)
        stageA(kt + 1, nb, 1);
        MMA(1, 0);
    }
    {   // peeled last tile: drain 4 -> 2 -> 0
        const int c = (NT - 1) & 1;
        wait_vmcnt<4>(); BAR();
        LD_A(0); LD_B(0);
        MMA(0, 0);
        wait_vmcnt<2>(); BAR();
        LD_B(1);
        MMA(0, 1);
        wait_vmcnt<0>(); BAR();
        LD_A(1);
        MMA(1, 1);
        MMA(1, 0);
    }

    // epilogue: C/D layout col=lane&15, row=quad*4+reg; rows >= M_ are pad
#pragma unroll
    for (int nf = 0; nf < 4; ++nf) {
        int gcn = n0 + wn * 64 + nf * 16 + lr;
        if (MODE == 1) {
            float bv = b0[gcn];
            float* of = (float*)o0;
#pragma unroll
            for (int mf = 0; mf < 8; ++mf) {
                int gr0 = m0 + wm * 128 + mf * 16 + quad * 4;
                if (gr0 >= M_) continue;
#pragma unroll
                for (int r = 0; r < 4; ++r)
                    of[(size_t)(gr0 + r) * C_ + gcn] = acc[mf][nf][r] + bv;
            }
        } else {
            int sec = gcn >> 10;  // uniform within a 16-col nf-tile
            int gcl = gcn & 1023;
            const float* bp = (sec == 0) ? b0 : (sec == 1) ? b1 : b2;
            float bv = bp[gcl];
            float osc = (sec == 0) ? 0.125f : 1.0f;
            int h = gcl >> 6, d = gcl & 63;
#pragma unroll
            for (int mf = 0; mf < 8; ++mf) {
                int gr0 = m0 + wm * 128 + mf * 16 + quad * 4;
                if (gr0 >= M_) continue;        // pad rows
                int b = gr0 / S_, s0 = gr0 - b * S_;  // never crosses batch
                if (sec < 2) {
                    f16* oq = (f16*)((sec == 0) ? o0 : o1);
#pragma unroll
                    for (int r = 0; r < 4; ++r) {
                        float v = (acc[mf][nf][r] + bv) * osc;
                        size_t idx = (((size_t)b * H_ + h) * S_ + (s0 + r)) * D_ + d;
                        oq[idx] = (f16)v;
                    }
                } else {
                    f16* ov = (f16*)o2;
                    f16x4 pk;
#pragma unroll
                    for (int r = 0; r < 4; ++r) pk[r] = (f16)(acc[mf][nf][r] + bv);
                    *(f16x4*)(ov + (((size_t)b * H_ + h) * D_ + d) * SP + s0) = pk;
                }
            }
        }
    }
}

// ---------------------------------------------------------------------------
// fp16 MFMA flash attention — round-6 structure + counted-vmcnt K/V double
// buffer (the proven gemm pattern): per tile t (buf c=t&1):
//   BAR        -- all waves done reading buf c^1 (tile t-1)
//   issue tile t+1's 4 loads/thread into c^1; vmcnt(4) drains tile t's loads
//              (tile t+1 stays in flight across compute — T4)
//   BAR        -- tile t visible
//   compute (S MFMA -> softmax -> PV MFMA; sP wave-private, no extra sync)
// LDS 48 KB (2x8K sK + 2x8K sVt + 16K sP) -> 3 blocks/CU.
// ---------------------------------------------------------------------------
__global__ __launch_bounds__(256) void attn_mfma(
    const f16* __restrict__ qg, const f16* __restrict__ kg,
    const f16* __restrict__ vt, f16* __restrict__ Y)
{
    __shared__ __align__(16) f16 sK[2][64 * 64];
    __shared__ __align__(16) f16 sVt[2][64 * 64];
    __shared__ __align__(16) f16 sP[4 * 32 * 64];  // per-wave P[q=32][key=64]

    const int tid = threadIdx.x;
    const int lin = blockIdx.x;
    const int xcd = lin & 7;
    const int pos = lin >> 3;
    const int bh = xcd * 64 + (pos >> 2);
    const int qt = 3 - (pos & 3);   // interleave long/short blocks
    const int q0 = qt * 128;
    const int lane = tid & 63, w = tid >> 6;
    const int quad = lane >> 4, lr = lane & 15;
    const size_t gbase = (size_t)bh * S_ * D_;
    const size_t vbase = (size_t)bh * D_ * SP;
    const int psw = (lr & 7) << 1;

    f16x8 qf[2][2];  // [t][s2]
#pragma unroll
    for (int t = 0; t < 2; ++t) {
        int q = q0 + w * 32 + t * 16 + lr;
        const f16* pq = qg + gbase + (size_t)q * D_;
#pragma unroll
        for (int s2 = 0; s2 < 2; ++s2)
            qf[t][s2] = *(const f16x8*)(pq + quad * 8 + 32 * s2);
    }

    f32x4 accO[2][4];
#pragma unroll
    for (int t = 0; t < 2; ++t)
#pragma unroll
        for (int nt = 0; nt < 4; ++nt) accO[t][nt] = (f32x4)0.f;
    float l_run[2] = {0.f, 0.f};

    const int NT = 2 * qt + 2;

    // issue the 4 async loads (2 K + 2 V per thread) of tile kt into buf
    auto stage = [&](int kt, int buf) __attribute__((always_inline)) {
        const int k0 = kt * 64;
#pragma unroll
        for (int it = 0; it < 2; ++it) {
            int idx = it * 256 + tid;
            int row = idx >> 3, c = idx & 7;
            int csw = (c ^ (row & 7)) * 8;
            async_load16(kg + gbase + (size_t)(k0 + row) * D_ + csw, &sK[buf][idx * 8]);
            async_load16(vt + vbase + (size_t)row * SP + k0 + csw, &sVt[buf][idx * 8]);
        }
    };

    auto step = [&](int kt, auto masked_tag) __attribute__((always_inline)) {
        constexpr bool MASKED = decltype(masked_tag)::value;
        const int cur = kt & 1;
        const int k0 = kt * 64;

        BAR();  // all waves done reading buf cur^1 -> safe to restage it
        if (kt + 1 < NT) {
            stage(kt + 1, cur ^ 1);
            wait_vmcnt<4>();  // drain tile kt's loads; kt+1 stays in flight
        } else {
            wait_vmcnt<0>();
        }
        BAR();  // tile kt visible to all waves

        // S^T = K·Q^T : 4 key-tiles x 2 q-tiles x 2 K-steps
        f32x4 accS[4][2];
#pragma unroll
        for (int mt = 0; mt < 4; ++mt)
#pragma unroll
            for (int t = 0; t < 2; ++t) accS[mt][t] = (f32x4)0.f;
        __builtin_amdgcn_s_setprio(1);
#pragma unroll
        for (int mt = 0; mt < 4; ++mt) {
            int row = mt * 16 + lr;
#pragma unroll
            for (int s2 = 0; s2 < 2; ++s2) {
                int off = row * 64 + (((quad + 4 * s2) ^ (lr & 7)) << 3);
                f16x8 ka = *(const f16x8*)&sK[cur][off];
#pragma unroll
                for (int t = 0; t < 2; ++t)
                    accS[mt][t] = __builtin_amdgcn_mfma_f32_16x16x32_f16(
                        ka, qf[t][s2], accS[mt][t], 0, 0, 0);
            }
        }
        __builtin_amdgcn_s_setprio(0);

        // exp (no max subtraction), accumulate l, pack P to wave-private LDS
        float ls[2] = {0.f, 0.f};
#pragma unroll
        for (int mt = 0; mt < 4; ++mt)
#pragma unroll
            for (int t = 0; t < 2; ++t) {
                f16x4 pk;
#pragma unroll
                for (int r = 0; r < 4; ++r) {
                    float s = accS[mt][t][r];
                    if (MASKED) {
                        int key = k0 + mt * 16 + quad * 4 + r;
                        int qq = q0 + w * 32 + t * 16 + lr;
                        s = (key <= qq && key < S_) ? s : -1e30f;
                    }
                    float p = __expf(s);
                    ls[t] += p;
                    pk[r] = (f16)p;
                }
                int c8 = (mt * 4 + quad) ^ psw;
                *(f16x4*)&sP[w * 2048 + (t * 16 + lr) * 64 + c8 * 4] = pk;
            }
        ls[0] += __shfl_xor(ls[0], 16); ls[0] += __shfl_xor(ls[0], 32);
        ls[1] += __shfl_xor(ls[1], 16); ls[1] += __shfl_xor(ls[1], 32);
        l_run[0] += ls[0];
        l_run[1] += ls[1];

        // O += P·V (A=P wave-private, B=Vt[cur])
        __builtin_amdgcn_s_setprio(1);
#pragma unroll
        for (int t = 0; t < 2; ++t) {
            int pb = w * 2048 + (t * 16 + lr) * 64;
#pragma unroll
            for (int s2 = 0; s2 < 2; ++s2) {
                int c8 = (quad * 2 + 8 * s2) ^ psw;
                f16x8 pf = *(const f16x8*)&sP[pb + c8 * 4];
#pragma unroll
                for (int nt = 0; nt < 4; ++nt) {
                    f16x8 vf = *(const f16x8*)
                        &sVt[cur][(nt * 16 + lr) * 64 + (((quad + 4 * s2) ^ (lr & 7)) << 3)];
                    accO[t][nt] = __builtin_amdgcn_mfma_f32_16x16x32_f16(
                        pf, vf, accO[t][nt], 0, 0, 0);
                }
            }
        }
        __builtin_amdgcn_s_setprio(0);
    };

    stage(0, 0);
    for (int kt = 0; kt < 2 * qt; ++kt) step(kt, MaskF{});
    step(2 * qt, MaskT{});
    step(2 * qt + 1, MaskT{});

    const int b = bh >> 4, h = bh & 15;
#pragma unroll
    for (int t = 0; t < 2; ++t) {
#pragma unroll
        for (int r = 0; r < 4; ++r) {
            float lsum = __shfl(l_run[t], quad * 4 + r);
            float iv = 1.f / lsum;
            int s = q0 + w * 32 + t * 16 + quad * 4 + r;
            if (s >= S_) continue;
            size_t rowbase = (size_t)(b * S_ + s) * C_ + h * 64;
#pragma unroll
            for (int nt = 0; nt < 4; ++nt)
                Y[rowbase + nt * 16 + lr] = (f16)(accO[t][nt][r] * iv);
        }
    }
}

// ---------------------------------------------------------------------------
// Workspace (fp16): q,k (2xNEL) + vt (B*H*D*SP) + xf (MP*C, pad rows zeroed,
// reused as yf) + wpf (WEL) ~ 134 MB. Wq/Wk/Wv casts in d_out scratch.
// 4 launches total: prep, gemm<0>, attn, gemm<1>.
// ---------------------------------------------------------------------------
extern "C" void kernel_launch(void* const* d_in, const int* in_sizes, int n_in,
                              void* d_out, int out_size, void* d_ws, size_t ws_size,
                              hipStream_t stream)
{
    const float* x = (const float*)d_in[0];
    const float* Wq = (const float*)d_in[1];
    const float* bq = (const float*)d_in[2];
    const float* Wk = (const float*)d_in[3];
    const float* bk = (const float*)d_in[4];
    const float* Wv = (const float*)d_in[5];
    const float* bv = (const float*)d_in[6];
    const float* Wp = (const float*)d_in[7];
    const float* bp = (const float*)d_in[8];

    const size_t NEL = (size_t)M_ * C_;
    const size_t WEL = (size_t)C_ * C_;
    f16* qf = (f16*)d_ws;
    f16* kf = qf + NEL;
    f16* vtw = kf + NEL;
    f16* xf = vtw + (size_t)B_ * H_ * D_ * SP;
    f16* wpf = xf + (size_t)MP * C_;
    f16* yf = xf;  // alias: x cast dead after QKV GEMM

    f16* wq = (f16*)d_out;  // d_out as scratch until final GEMM
    f16* wk = wq + WEL;
    f16* wv = wk + WEL;

    hipFuncSetAttribute(reinterpret_cast<const void*>(&gemm256<0>),
                        hipFuncAttributeMaxDynamicSharedMemorySize, 131072);
    hipFuncSetAttribute(reinterpret_cast<const void*>(&gemm256<1>),
                        hipFuncAttributeMaxDynamicSharedMemorySize, 131072);

    int n8r = (int)(NEL / 8);
    int n8t = (int)((size_t)MP * C_ / 8);
    int nprep = 4096 + (n8t + 255) / 256;
    prep<<<nprep, 256, 0, stream>>>(x, xf, n8r, n8t,
                                    Wq, Wk, Wv, Wp, wq, wk, wv, wpf);

    // fused QKV projection: N=3072, Q section carries the 0.125 softmax scale
    gemm256<0><<<756, 512, 131072, stream>>>(xf, wq, bq, bk, bv, qf, kf, vtw);

    attn_mfma<<<2048, 256, 0, stream>>>(qf, kf, vtw, yf);

    gemm256<1><<<252, 512, 131072, stream>>>(yf, wpf, bp, nullptr, nullptr,
                                             d_out, nullptr, nullptr);
}